// Round 21
// baseline (97.575 us; speedup 1.0000x reference)
//
#include <hip/hip_runtime.h>

#define T64   64
#define SLEN  1024
#define NSCANB 4096       // 8 octants x 512 batches

typedef float f32x4  __attribute__((ext_vector_type(4)));
typedef short bf16x8 __attribute__((ext_vector_type(8)));

typedef const __attribute__((address_space(1))) void GV;
typedef __attribute__((address_space(3))) void LV;

static __device__ __forceinline__ short f2bf_rne(float f) {
  unsigned u = __builtin_bit_cast(unsigned, f);
  u += 0x7FFFu + ((u >> 16) & 1u);
  return (short)(u >> 16);
}
static __device__ __forceinline__ unsigned pkbf(float lo, float hi) {
  return __builtin_amdgcn_perm(__builtin_bit_cast(unsigned, hi),
                               __builtin_bit_cast(unsigned, lo), 0x07060302u);
}
static __device__ __forceinline__ bf16x8 packB(f32x4 a, f32x4 b) {
  union { unsigned u[4]; bf16x8 v; } r;
  r.u[0] = pkbf(a[0], a[1]); r.u[1] = pkbf(a[2], a[3]);
  r.u[2] = pkbf(b[0], b[1]); r.u[3] = pkbf(b[2], b[3]);
  return r.v;
}
static __device__ __forceinline__ f32x4 exp4(f32x4 x) {
  f32x4 r; r[0]=__expf(x[0]); r[1]=__expf(x[1]); r[2]=__expf(x[2]); r[3]=__expf(x[3]);
  return r;
}

#define MF(a, b, c) __builtin_amdgcn_mfma_f32_16x16x32_bf16((a), (b), (c), 0, 0, 0)

// ---------------------------------------------------------------------------
// Prep: one block precomputes the MFMA A-fragments (exp(trans), fwd layout)
// for every lane: wsA[lane][frag = mt*2+kc] = bf16x8. Removes the per-scan-
// wave 64-gather+64-expf A-fill (R20 regression component).
// ---------------------------------------------------------------------------
__global__ __launch_bounds__(64) void crf_prep(const float* __restrict__ trans,
                                               short* __restrict__ wsA)
{
  const int lane = threadIdx.x;
  const int g = lane >> 4, c = lane & 15;
#pragma unroll
  for (int mt = 0; mt < 4; ++mt)
#pragma unroll
    for (int kc = 0; kc < 2; ++kc) {
      short v[8];
#pragma unroll
      for (int e = 0; e < 8; ++e) {
        int to = 16 * (c >> 2) + 4 * mt + (c & 3);
        int ti = 16 * g + 8 * kc + e;
        v[e] = f2bf_rne(__expf(trans[ti * T64 + to]));
      }
#pragma unroll
      for (int e = 0; e < 8; ++e)
        wsA[(lane * 8 + mt * 2 + kc) * 8 + e] = v[e];
    }
}

// ---------------------------------------------------------------------------
// Fused kernel — burst-staged scan (R20 post-mortem: the 1.6 TB/s wall
// follows the interleaved-fine-stream PATTERN; restructure each wave into
// ONE contiguous 34.8KB burst, then compute entirely from LDS).
//  blocks [0, NSCANB): scan. Block (b = blk>>3, oct = blk&7): stages rows
//    [128*oct - 8, 128*oct + 128) (136 rows, clamped at 0) via 34
//    back-to-back 1KB DMAs (pre-swizzled source slot ^= (r>>3)&7, linear
//    dest), vmcnt(0) once. Then 16 steps (warm 8 + owned 8 per chain,
//    chain c owns rows 128*oct + 8c .. +7) with zero HBM traffic.
//    Renorm: s==7 RESET (warm scale discarded), s==15 ACCUM.
//    oct0/c0: garbage warm, exact-init overwrite at s==8 (t==0).
//  blocks [NSCANB, NSCANB+B): gold (numerator), concurrent.
// ---------------------------------------------------------------------------
__global__ __launch_bounds__(64) void crf_fused(
    const float* __restrict__ em, const float* __restrict__ mask,
    const float* __restrict__ start_tr, const float* __restrict__ end_tr,
    const float* __restrict__ trans, const int* __restrict__ tags,
    const short* __restrict__ wsA,
    float* __restrict__ wsF, float* __restrict__ accZ,
    float* __restrict__ accG)
{
  __shared__ float emlds[136 * 64];   // 136 rows x 256B = 34,816 B

  if (blockIdx.x < NSCANB) {
    // ------------------------------ scan ---------------------------------
    const int lane = threadIdx.x;
    const int g = lane >> 4, c = lane & 15;
    const int oct = blockIdx.x & 7;
    const int b   = blockIdx.x >> 3;
    const float* embase = em + (size_t)b * (SLEN * T64);
    const int R0 = 128 * oct;

    // ---- staging burst: 34 x 1KB contiguous DMAs (local rows 0..135) ----
#pragma unroll
    for (int d = 0; d < 34; ++d) {
      int rloc = 4 * d + (lane >> 4);
      int grow = R0 - 8 + rloc;
      grow = grow < 0 ? 0 : grow;
      unsigned sslot = (unsigned)((lane & 15) ^ ((rloc >> 3) & 7));
      const char* src = (const char*)embase + (size_t)grow * 256 + (sslot << 4);
      __builtin_amdgcn_global_load_lds((GV*)src,
          (LV*)((char*)emlds + d * 1024), 16, 0, 0);
    }

    // A fragments from prep table (L2-hot, 8 x 16B)
    bf16x8 A00, A01, A10, A11, A20, A21, A30, A31;
    {
      const bf16x8* ap = (const bf16x8*)(wsA) + lane * 8;
      A00 = ap[0]; A01 = ap[1]; A10 = ap[2]; A11 = ap[3];
      A20 = ap[4]; A21 = ap[5]; A30 = ap[6]; A31 = ap[7];
    }

    // exact-init values for chain oct0/c0 (only c==0 lanes consume at s==8)
    f32x4 e0q0 = {0,0,0,0}, e0q1 = {0,0,0,0}, e0q2 = {0,0,0,0}, e0q3 = {0,0,0,0};
    if (oct == 0) {
      const float* r0 = embase + 16 * g;        // t = 0 row
      f32x4 v0 = *(const f32x4*)(r0 + 0),  v1 = *(const f32x4*)(r0 + 4);
      f32x4 v2 = *(const f32x4*)(r0 + 8),  v3 = *(const f32x4*)(r0 + 12);
#pragma unroll
      for (int r = 0; r < 4; ++r) {
        e0q0[r] = __expf(start_tr[16 * g + 0  + r] + v0[r]);
        e0q1[r] = __expf(start_tr[16 * g + 4  + r] + v1[r]);
        e0q2[r] = __expf(start_tr[16 * g + 8  + r] + v2[r]);
        e0q3[r] = __expf(start_tr[16 * g + 12 + r] + v3[r]);
      }
    }

    f32x4 q0 = {1,1,1,1}, q1 = {1,1,1,1}, q2 = {1,1,1,1}, q3 = {1,1,1,1};
    bf16x8 B0 = packB(q0, q1), B1 = packB(q2, q3);

    asm volatile("s_waitcnt vmcnt(0)" ::: "memory");   // burst landed
    __builtin_amdgcn_sched_barrier(0);

    const f32x4 zz = {0.f, 0.f, 0.f, 0.f};
    float ls = 0.0f;

    // step s: chain c reads local row r = 8c + s (swizzled slots);
    // RN: 0 none, 1 reset (end of warm), 2 accumulate
#define STEP(S, RN)                                                           \
    {                                                                         \
      const int r_ = 8 * c + (S);                                             \
      const unsigned xw_ = ((unsigned)((r_ >> 3) & 7)) << 4;                  \
      const char* sb_ = (const char*)emlds + r_ * 256;                        \
      f32x4 E0 = *(const f32x4*)(sb_ + (((unsigned)((g * 4 + 0) << 4)) ^ xw_)); \
      f32x4 E1 = *(const f32x4*)(sb_ + (((unsigned)((g * 4 + 1) << 4)) ^ xw_)); \
      f32x4 E2 = *(const f32x4*)(sb_ + (((unsigned)((g * 4 + 2) << 4)) ^ xw_)); \
      f32x4 E3 = *(const f32x4*)(sb_ + (((unsigned)((g * 4 + 3) << 4)) ^ xw_)); \
      f32x4 d0 = MF(A00, B0, zz), d1 = MF(A10, B0, zz);                       \
      f32x4 d2 = MF(A20, B0, zz), d3 = MF(A30, B0, zz);                       \
      d0 = MF(A01, B1, d0); d1 = MF(A11, B1, d1);                             \
      d2 = MF(A21, B1, d2); d3 = MF(A31, B1, d3);                             \
      q0 = d0 * exp4(E0); q1 = d1 * exp4(E1);                                 \
      q2 = d2 * exp4(E2); q3 = d3 * exp4(E3);                                 \
      if ((S) == 8 && oct == 0) {               /* t==0: exact init, c==0 */  \
        bool z = (c == 0);                                                    \
        q0 = z ? e0q0 : q0; q1 = z ? e0q1 : q1;                               \
        q2 = z ? e0q2 : q2; q3 = z ? e0q3 : q3;                               \
      }                                                                       \
      if (RN) {                                                               \
        float zt = ((q0[0]+q0[1])+(q0[2]+q0[3])) + ((q1[0]+q1[1])+(q1[2]+q1[3]))  \
                 + ((q2[0]+q2[1])+(q2[2]+q2[3])) + ((q3[0]+q3[1])+(q3[2]+q3[3])); \
        zt += __shfl_xor(zt, 16, 64);           /* sum over g -> per-chain */ \
        zt += __shfl_xor(zt, 32, 64);                                         \
        float rz = __builtin_amdgcn_rcpf(zt);                                 \
        if ((RN) == 2) ls += __logf(zt);        /* warm scale discarded */    \
        f32x4 rzv = {rz, rz, rz, rz};                                         \
        q0 *= rzv; q1 *= rzv; q2 *= rzv; q3 *= rzv;                           \
      }                                                                       \
      B0 = packB(q0, q1); B1 = packB(q2, q3);                                 \
    }

    STEP(0, 0) STEP(1, 0) STEP(2, 0)  STEP(3, 0)  STEP(4, 0)  STEP(5, 0)
    STEP(6, 0) STEP(7, 1) STEP(8, 0)  STEP(9, 0)  STEP(10, 0) STEP(11, 0)
    STEP(12, 0) STEP(13, 0) STEP(14, 0) STEP(15, 2)
#undef STEP

    // final state of the whole sequence = oct==7, chain c==15 (t=1023),
    // renormed at s==15 -> stored normalized
    if (oct == 7 && c == 15) {
      *(f32x4*)(wsF + (size_t)b * T64 + 16 * g + 0)  = q0;
      *(f32x4*)(wsF + (size_t)b * T64 + 16 * g + 4)  = q1;
      *(f32x4*)(wsF + (size_t)b * T64 + 16 * g + 8)  = q2;
      *(f32x4*)(wsF + (size_t)b * T64 + 16 * g + 12) = q3;
    }
    // sum per-chain ls over the wave's 16 chains, add once
    ls += __shfl_xor(ls, 1, 64);
    ls += __shfl_xor(ls, 2, 64);
    ls += __shfl_xor(ls, 4, 64);
    ls += __shfl_xor(ls, 8, 64);
    if (lane == 0) atomicAdd(accZ, ls);

  } else {
    // ------------------------------ gold ---------------------------------
    const int wid  = blockIdx.x - NSCANB;       // batch index
    const int lane = threadIdx.x;
    const int*   tg = tags + (size_t)wid * SLEN;
    const float* mk = mask + (size_t)wid * SLEN;
    const float* eb = em + (size_t)wid * SLEN * T64;

    float part = 0.f, pm = 0.f;
    for (int it = 0; it < SLEN / 64; ++it) {
      int   t   = it * 64 + lane;
      int   tag = tg[t];
      float m   = mk[t];
      pm += m;
      if (t == 0) {
        part += start_tr[tag] + eb[tag];
      } else {
        int tp = tg[t - 1];
        part += (eb[(size_t)t * T64 + tag] + trans[tp * T64 + tag]) * m;
      }
    }
#pragma unroll
    for (int d = 1; d < 64; d <<= 1) pm += __shfl_xor(pm, d, 64);
#pragma unroll
    for (int d = 1; d < 64; d <<= 1) part += __shfl_xor(part, d, 64);
    if (lane == 0) {
      int last = (int)pm - 1;                   // mask sums are exact ints
      part += end_tr[tg[last]];
      atomicAdd(accG, part);
    }
  }
}

// ---------------------------------------------------------------------------
// Combine: per batch add log(sum_j exp(end_j) * pF[b][j]) to accZ.
// ---------------------------------------------------------------------------
__global__ void crf_combine(const float* __restrict__ wsF,
                            const float* __restrict__ end_tr,
                            float* __restrict__ accZ)
{
  const int wid  = (blockIdx.x * blockDim.x + threadIdx.x) >> 6;
  const int j    = threadIdx.x & 63;
  float v = wsF[(size_t)wid * T64 + j] * __expf(end_tr[j]);
#pragma unroll
  for (int d = 1; d < 64; d <<= 1) v += __shfl_xor(v, d, 64);
  if (j == 0) atomicAdd(accZ, __logf(v));
}

__global__ void crf_init(float* __restrict__ ws) { ws[0] = 0.f; ws[1] = 0.f; }

__global__ void crf_final(float* __restrict__ out, const float* __restrict__ ws)
{ out[0] = ws[0] - ws[1]; }

// ---------------------------------------------------------------------------
extern "C" void kernel_launch(void* const* d_in, const int* in_sizes, int n_in,
                              void* d_out, int out_size, void* d_ws, size_t ws_size,
                              hipStream_t stream)
{
  const float* em   = (const float*)d_in[0];
  const float* mask = (const float*)d_in[1];
  const float* st   = (const float*)d_in[2];
  const float* en   = (const float*)d_in[3];
  const float* tr   = (const float*)d_in[4];
  const int*   tags = (const int*)d_in[5];
  float* out = (float*)d_out;
  float* ws  = (float*)d_ws;

  const int B = in_sizes[1] / SLEN;             // 512

  float* accG = ws;                             // ws[0]
  float* accZ = ws + 1;                         // ws[1]
  float* wsF  = ws + 64;                        // 512*64 floats
  short* wsA  = (short*)(ws + 64 + 512 * 64);   // 64 lanes x 8 frags x 8 bf16

  crf_init<<<1, 1, 0, stream>>>(ws);
  crf_prep<<<1, 64, 0, stream>>>(tr, wsA);
  crf_fused<<<NSCANB + B, 64, 0, stream>>>(em, mask, st, en, tr, tags,
                                           wsA, wsF, accZ, accG);
  crf_combine<<<B / 4, 256, 0, stream>>>(wsF, en, accZ);
  crf_final<<<1, 1, 0, stream>>>(out, ws);
}

// Round 22
// 61.198 us; speedup vs baseline: 1.5944x; 1.5944x over previous
//
#include <hip/hip_runtime.h>

#define T64   64
#define SLEN  1024
#define NSCANB 1024       // 2 half-blocks x 512 batches

typedef float f32x4  __attribute__((ext_vector_type(4)));
typedef short bf16x8 __attribute__((ext_vector_type(8)));

typedef const __attribute__((address_space(1))) void GV;
typedef __attribute__((address_space(3))) void LV;

static __device__ __forceinline__ short f2bf_rne(float f) {
  unsigned u = __builtin_bit_cast(unsigned, f);
  u += 0x7FFFu + ((u >> 16) & 1u);
  return (short)(u >> 16);
}
static __device__ __forceinline__ unsigned pkbf(float lo, float hi) {
  return __builtin_amdgcn_perm(__builtin_bit_cast(unsigned, hi),
                               __builtin_bit_cast(unsigned, lo), 0x07060302u);
}
static __device__ __forceinline__ bf16x8 packB(f32x4 a, f32x4 b) {
  union { unsigned u[4]; bf16x8 v; } r;
  r.u[0] = pkbf(a[0], a[1]); r.u[1] = pkbf(a[2], a[3]);
  r.u[2] = pkbf(b[0], b[1]); r.u[3] = pkbf(b[2], b[3]);
  return r.v;
}
static __device__ __forceinline__ f32x4 exp4(f32x4 x) {
  f32x4 r; r[0]=__expf(x[0]); r[1]=__expf(x[1]); r[2]=__expf(x[2]); r[3]=__expf(x[3]);
  return r;
}

#define MF(a, b, c) __builtin_amdgcn_mfma_f32_16x16x32_bf16((a), (b), (c), 0, 0, 0)

// ---------------------------------------------------------------------------
// Fused kernel — session-best configuration (R18, 61.4 us), reverted after
// R19-R21 refuted load-path / occupancy / burst-structure hypotheses.
//  blocks [0, NSCANB): scan. Block (b = blk>>1, h = blk&1): 16 chains
//    c = 0..15 cover t in [512h+32c, 512h+32c+32), warm 8. 40 steps =
//    20 supersteps of 2. Ring: 2 slots x 8 pair-chunks x 1KB = 16 KB.
//    One DMA = two chains' 512B chunks (half-wave each), per-lane
//    pre-swizzled source, linear LDS dest. vmcnt(8) steady, vmcnt(0) last.
//    chain h0c0: garbage warm, exact-init overwrite at s==8 (ssi==4,k==0).
//  blocks [NSCANB, NSCANB+B): gold (numerator), concurrent (R15 lesson:
//    no gathers inside the scan loop).
// ---------------------------------------------------------------------------
__global__ __launch_bounds__(64) void crf_fused(
    const float* __restrict__ em, const float* __restrict__ mask,
    const float* __restrict__ start_tr, const float* __restrict__ end_tr,
    const float* __restrict__ trans, const int* __restrict__ tags,
    float* __restrict__ wsF, float* __restrict__ accZ,
    float* __restrict__ accG)
{
  __shared__ float ring[2 * 8 * 256];    // 2 slots x 8 x 1KB = 16 KB

  if (blockIdx.x < NSCANB) {
    // ------------------------------ scan ---------------------------------
    const int lane = threadIdx.x;
    const int g = lane >> 4, c = lane & 15;
    const unsigned cswz = (unsigned)((c & 7) << 4);
    const int h = blockIdx.x & 1;
    const int b = blockIdx.x >> 1;
    const float* embase = em + (size_t)b * (SLEN * T64);

    // A fragments (fwd): out tau' = 16*(c>>2)+4*mt+(c&3); in tau = 16*g+8*kc+e
    bf16x8 A00, A01, A10, A11, A20, A21, A30, A31;
#define FILLA(MT, KC, DST)                                                    \
    { bf16x8 a;                                                               \
      _Pragma("unroll")                                                       \
      for (int e = 0; e < 8; ++e) {                                           \
        int to = 16 * (c >> 2) + 4 * (MT) + (c & 3);                          \
        int ti = 16 * g + 8 * (KC) + e;                                       \
        a[e] = f2bf_rne(__expf(trans[ti * T64 + to]));                        \
      }                                                                       \
      DST = a; }
    FILLA(0, 0, A00) FILLA(0, 1, A01) FILLA(1, 0, A10) FILLA(1, 1, A11)
    FILLA(2, 0, A20) FILLA(2, 1, A21) FILLA(3, 0, A30) FILLA(3, 1, A31)
#undef FILLA

    // exact-init values for chain h0c0 (only c==0 lanes consume at s==8)
    f32x4 e0q0 = {0,0,0,0}, e0q1 = {0,0,0,0}, e0q2 = {0,0,0,0}, e0q3 = {0,0,0,0};
    if (h == 0) {
      const float* r0 = embase + 16 * g;        // t = 0 row
      f32x4 v0 = *(const f32x4*)(r0 + 0),  v1 = *(const f32x4*)(r0 + 4);
      f32x4 v2 = *(const f32x4*)(r0 + 8),  v3 = *(const f32x4*)(r0 + 12);
#pragma unroll
      for (int r = 0; r < 4; ++r) {
        e0q0[r] = __expf(start_tr[16 * g + 0  + r] + v0[r]);
        e0q1[r] = __expf(start_tr[16 * g + 4  + r] + v1[r]);
        e0q2[r] = __expf(start_tr[16 * g + 8  + r] + v2[r]);
        e0q3[r] = __expf(start_tr[16 * g + 12 + r] + v3[r]);
      }
    }

    f32x4 q0 = {1,1,1,1}, q1 = {1,1,1,1}, q2 = {1,1,1,1}, q3 = {1,1,1,1};
    bf16x8 B0 = packB(q0, q1), B1 = packB(q2, q3);

    // superstep SSI covers steps {2*SSI, 2*SSI+1}; chain ca's chunk = rows
    // tc..tc+1, tc = 512h + 32*ca - 8 + 2*SSI (clamped >= 0).
    // DMA p: lanes<32 -> chain 2p, lanes>=32 -> chain 2p+1; 512B each,
    // source pre-swizzled (XOR bits 4-6), dest linear p*1024 + lane*16.
#define ISSUE8(SSI, SLOT)                                                     \
    { _Pragma("unroll")                                                       \
      for (int p = 0; p < 8; ++p) {                                          \
        int ca = 2 * p + (lane >> 5);                                        \
        int tc = 512 * h + 32 * ca - 8 + 2 * (SSI);                          \
        tc = tc < 0 ? 0 : tc;                                                \
        unsigned so = ((unsigned)((lane & 31) * 16)) ^                        \
                      ((unsigned)((ca & 7) << 4));                            \
        const char* src = (const char*)embase + (size_t)tc * 256 + so;        \
        __builtin_amdgcn_global_load_lds((GV*)src,                            \
            (LV*)((char*)ring + (SLOT) * 8192 + p * 1024), 16, 0, 0);         \
      } }

    ISSUE8(0, 0) ISSUE8(1, 1)                   // prologue: 16 DMAs out

    const f32x4 zz = {0.f, 0.f, 0.f, 0.f};
    float ls = 0.0f;

    for (int ssi = 0; ssi < 20; ++ssi) {
      if (ssi == 19) { asm volatile("s_waitcnt vmcnt(0)" ::: "memory"); }
      else           { asm volatile("s_waitcnt vmcnt(8)" ::: "memory"); }
      __builtin_amdgcn_sched_barrier(0);

      // LDS->reg: E[k][mt], swizzled read from chain c's 512B chunk
      const char* sb = (const char*)ring + (ssi & 1) * 8192
                       + (c >> 1) * 1024 + (c & 1) * 512;
      f32x4 E[2][4];
#pragma unroll
      for (int k = 0; k < 2; ++k)
#pragma unroll
        for (int mt = 0; mt < 4; ++mt)
          E[k][mt] = *(const f32x4*)(sb +
              (((unsigned)(k * 256 + g * 64 + 16 * mt)) ^ cswz));

#pragma unroll
      for (int k = 0; k < 2; ++k) {
        f32x4 d0 = MF(A00, B0, zz), d1 = MF(A10, B0, zz);
        f32x4 d2 = MF(A20, B0, zz), d3 = MF(A30, B0, zz);
        d0 = MF(A01, B1, d0); d1 = MF(A11, B1, d1);
        d2 = MF(A21, B1, d2); d3 = MF(A31, B1, d3);
        q0 = d0 * exp4(E[k][0]); q1 = d1 * exp4(E[k][1]);
        q2 = d2 * exp4(E[k][2]); q3 = d3 * exp4(E[k][3]);

        if (ssi == 4 && k == 0 && h == 0) {     // s==8: exact init for c==0
          bool z = (c == 0);
          q0 = z ? e0q0 : q0; q1 = z ? e0q1 : q1;
          q2 = z ? e0q2 : q2; q3 = z ? e0q3 : q3;
        }

        if (k == 1 && (ssi & 3) == 3) {         // s==7 mod 8: per-chain renorm
          float zt = ((q0[0]+q0[1])+(q0[2]+q0[3])) + ((q1[0]+q1[1])+(q1[2]+q1[3]))
                   + ((q2[0]+q2[1])+(q2[2]+q2[3])) + ((q3[0]+q3[1])+(q3[2]+q3[3]));
          zt += __shfl_xor(zt, 16, 64);         // sum over g -> per-chain
          zt += __shfl_xor(zt, 32, 64);
          float rz = __builtin_amdgcn_rcpf(zt);
          ls = (ssi == 3) ? 0.f : ls + __logf(zt);  // warm scale discarded
          f32x4 rzv = {rz, rz, rz, rz};
          q0 *= rzv; q1 *= rzv; q2 *= rzv; q3 *= rzv;
        }
        B0 = packB(q0, q1); B1 = packB(q2, q3);
      }

      if (ssi + 2 < 20) {                       // refill just-consumed slot
        asm volatile("s_waitcnt lgkmcnt(0)" ::: "memory");
        __builtin_amdgcn_sched_barrier(0);
        ISSUE8(ssi + 2, (ssi & 1))
      }
    }
#undef ISSUE8

    // final state of the whole sequence = block h==1, chains c==15
    // (state renormed at the final step; stored normalized)
    if (h == 1 && c == 15) {
      *(f32x4*)(wsF + (size_t)b * T64 + 16 * g + 0)  = q0;
      *(f32x4*)(wsF + (size_t)b * T64 + 16 * g + 4)  = q1;
      *(f32x4*)(wsF + (size_t)b * T64 + 16 * g + 8)  = q2;
      *(f32x4*)(wsF + (size_t)b * T64 + 16 * g + 12) = q3;
    }
    // sum per-chain ls over the wave's 16 chains, add once
    ls += __shfl_xor(ls, 1, 64);
    ls += __shfl_xor(ls, 2, 64);
    ls += __shfl_xor(ls, 4, 64);
    ls += __shfl_xor(ls, 8, 64);
    if (lane == 0) atomicAdd(accZ, ls);

  } else {
    // ------------------------------ gold ---------------------------------
    const int wid  = blockIdx.x - NSCANB;       // batch index
    const int lane = threadIdx.x;
    const int*   tg = tags + (size_t)wid * SLEN;
    const float* mk = mask + (size_t)wid * SLEN;
    const float* eb = em + (size_t)wid * SLEN * T64;

    float part = 0.f, pm = 0.f;
    for (int it = 0; it < SLEN / 64; ++it) {
      int   t   = it * 64 + lane;
      int   tag = tg[t];
      float m   = mk[t];
      pm += m;
      if (t == 0) {
        part += start_tr[tag] + eb[tag];
      } else {
        int tp = tg[t - 1];
        part += (eb[(size_t)t * T64 + tag] + trans[tp * T64 + tag]) * m;
      }
    }
#pragma unroll
    for (int d = 1; d < 64; d <<= 1) pm += __shfl_xor(pm, d, 64);
#pragma unroll
    for (int d = 1; d < 64; d <<= 1) part += __shfl_xor(part, d, 64);
    if (lane == 0) {
      int last = (int)pm - 1;                   // mask sums are exact ints
      part += end_tr[tg[last]];
      atomicAdd(accG, part);
    }
  }
}

// ---------------------------------------------------------------------------
// Combine: per batch add log(sum_j exp(end_j) * pF[b][j]) to accZ.
// ---------------------------------------------------------------------------
__global__ void crf_combine(const float* __restrict__ wsF,
                            const float* __restrict__ end_tr,
                            float* __restrict__ accZ)
{
  const int wid  = (blockIdx.x * blockDim.x + threadIdx.x) >> 6;
  const int j    = threadIdx.x & 63;
  float v = wsF[(size_t)wid * T64 + j] * __expf(end_tr[j]);
#pragma unroll
  for (int d = 1; d < 64; d <<= 1) v += __shfl_xor(v, d, 64);
  if (j == 0) atomicAdd(accZ, __logf(v));
}

__global__ void crf_init(float* __restrict__ ws) { ws[0] = 0.f; ws[1] = 0.f; }

__global__ void crf_final(float* __restrict__ out, const float* __restrict__ ws)
{ out[0] = ws[0] - ws[1]; }

// ---------------------------------------------------------------------------
extern "C" void kernel_launch(void* const* d_in, const int* in_sizes, int n_in,
                              void* d_out, int out_size, void* d_ws, size_t ws_size,
                              hipStream_t stream)
{
  const float* em   = (const float*)d_in[0];
  const float* mask = (const float*)d_in[1];
  const float* st   = (const float*)d_in[2];
  const float* en   = (const float*)d_in[3];
  const float* tr   = (const float*)d_in[4];
  const int*   tags = (const int*)d_in[5];
  float* out = (float*)d_out;
  float* ws  = (float*)d_ws;

  const int B = in_sizes[1] / SLEN;             // 512

  float* accG = ws;                             // ws[0]
  float* accZ = ws + 1;                         // ws[1]
  float* wsF  = ws + 64;

  crf_init<<<1, 1, 0, stream>>>(ws);
  crf_fused<<<NSCANB + B, 64, 0, stream>>>(em, mask, st, en, tr, tags,
                                           wsF, accZ, accG);
  crf_combine<<<B / 4, 256, 0, stream>>>(wsF, en, accZ);
  crf_final<<<1, 1, 0, stream>>>(out, ws);
}